// Round 3
// baseline (927.750 us; speedup 1.0000x reference)
//
#include <hip/hip_runtime.h>
#include <math.h>

#define T_SEQ 4096
#define HID 2048
#define FFN1 1408
#define TWO_FFN 2816
#define NE 8
#define NSLOT 8192   // T_SEQ * TOP_K
#define MAXT 40      // max live m-tiles at 256-granule: 8192/256 + 8 (exact bound)

typedef unsigned short u16;
typedef __bf16 bf16x8_t __attribute__((ext_vector_type(8)));
typedef float f32x4_t __attribute__((ext_vector_type(4)));

__device__ __forceinline__ u16 f2bf(float f) {
    union { float f; unsigned int u; } v; v.f = f;
    unsigned int u = v.u;
    unsigned int r = u + 0x7FFFu + ((u >> 16) & 1u);
    return (u16)(r >> 16);
}
__device__ __forceinline__ float bf2f(u16 b) {
    union { unsigned int u; float f; } v; v.u = ((unsigned int)b) << 16;
    return v.f;
}
__device__ __forceinline__ unsigned pack2(float a, float b) {
    return (unsigned)f2bf(a) | ((unsigned)f2bf(b) << 16);
}

// ---------------- fp32 -> bf16 bulk convert (8 elems/thread) ----------------
__global__ __launch_bounds__(256) void cvt_kernel(const float* __restrict__ in,
                                                  u16* __restrict__ out, long n) {
    long i = ((long)blockIdx.x * 256 + threadIdx.x) * 8;
    if (i + 8 > n) return;
    const float4* p = (const float4*)(in + i);
    float4 a = p[0], b = p[1];
    uint4 o;
    o.x = pack2(a.x, a.y);
    o.y = pack2(a.z, a.w);
    o.z = pack2(b.x, b.y);
    o.w = pack2(b.z, b.w);
    *(uint4*)(out + i) = o;
}

// ---------------- router: logits, top-2, weights, counts ----------------
__global__ __launch_bounds__(256) void router_kernel(
    const float* __restrict__ x, const float* __restrict__ gw,
    float* __restrict__ logits_out, int* __restrict__ pairs,
    float2* __restrict__ wts, int* __restrict__ counts) {
    int wave = threadIdx.x >> 6, lane = threadIdx.x & 63;
    int t = blockIdx.x * 4 + wave;
    float acc[NE] = {0.f,0.f,0.f,0.f,0.f,0.f,0.f,0.f};
    const float* xr = x + (long)t * HID;
    for (int i = 0; i < HID / 64; ++i) {
        int hh = i * 64 + lane;
        float xv = xr[hh];
        const float4* g4 = (const float4*)(gw + (long)hh * NE);
        float4 g0 = g4[0], g1 = g4[1];
        acc[0] += xv * g0.x; acc[1] += xv * g0.y;
        acc[2] += xv * g0.z; acc[3] += xv * g0.w;
        acc[4] += xv * g1.x; acc[5] += xv * g1.y;
        acc[6] += xv * g1.z; acc[7] += xv * g1.w;
    }
    #pragma unroll
    for (int m = 1; m < 64; m <<= 1) {
        #pragma unroll
        for (int e = 0; e < NE; ++e) acc[e] += __shfl_xor(acc[e], m, 64);
    }
    if (lane == 0) {
        float* lo = logits_out + (long)t * NE;
        #pragma unroll
        for (int e = 0; e < NE; ++e) lo[e] = acc[e];
        int a = 0; float va = acc[0];
        #pragma unroll
        for (int e = 1; e < NE; ++e) if (acc[e] > va) { va = acc[e]; a = e; }
        int b = -1; float vb = 0.f;
        #pragma unroll
        for (int e = 0; e < NE; ++e) {
            if (e == a) continue;
            if (b < 0 || acc[e] > vb) { vb = acc[e]; b = e; }
        }
        float w0 = 1.0f / (1.0f + expf(vb - va));
        pairs[t] = a | (b << 8);
        wts[t] = make_float2(w0, 1.0f - w0);
        atomicAdd(counts + a, 1);
        atomicAdd(counts + b, 1);
    }
}

// ------- prefix offsets + live-tile table (one wave, shfl scans) -------
__global__ void offsets_kernel(const int* __restrict__ counts, int* __restrict__ offs,
                               int* __restrict__ tiles) {
    int lane = threadIdx.x;   // 64 threads
    int c = (lane < NE) ? counts[lane] : 0;
    int s = c;
    #pragma unroll
    for (int m = 1; m < NE; m <<= 1) {
        int t = __shfl_up(s, m, 64);
        if (lane >= m) s += t;
    }
    if (lane < NE) offs[lane] = s - c;
    if (lane == NE - 1) offs[NE] = s;
    int nt = (lane < NE) ? ((c + 255) >> 8) : 0;   // 256-row m-tiles
    int ts = nt;
    #pragma unroll
    for (int m = 1; m < NE; m <<= 1) {
        int t = __shfl_up(ts, m, 64);
        if (lane >= m) ts += t;
    }
    int tbase = ts - nt;
    if (lane < NE)
        for (int i = 0; i < nt; ++i) tiles[tbase + i] = (lane << 20) | (i << 8);
    int nt_tot = __shfl(ts, NE - 1, 64);
    for (int j = lane; j < MAXT; j += 64)
        if (j >= nt_tot) tiles[j] = -1;
}

// ---------------- scatter tokens into compact expert segments ----------------
__global__ __launch_bounds__(256) void scatter_kernel(
    const int* __restrict__ pairs, const int* __restrict__ offs,
    int* __restrict__ cursor, int* __restrict__ tok_of, int* __restrict__ inv) {
    int t = blockIdx.x * 256 + threadIdx.x;
    if (t >= T_SEQ) return;
    int pr = pairs[t];
    int a = pr & 0xFF, b = (pr >> 8) & 0xFF;
    int p0 = atomicAdd(cursor + a, 1);
    int s0 = offs[a] + p0;
    tok_of[s0] = t; inv[2 * t] = s0;
    int p1 = atomicAdd(cursor + b, 1);
    int s1 = offs[b] + p1;
    tok_of[s1] = t; inv[2 * t + 1] = s1;
}

// ---------------- gather hidden rows to compact bf16 A ----------------
__global__ __launch_bounds__(256) void gather_kernel(
    const float* __restrict__ x, const int* __restrict__ tok_of, u16* __restrict__ Ab) {
    int slot = blockIdx.x;
    int tok = tok_of[slot];
    int c = threadIdx.x * 8;
    const float4* p = (const float4*)(x + (long)tok * HID + c);
    float4 a = p[0], b = p[1];
    uint4 o;
    o.x = pack2(a.x, a.y);
    o.y = pack2(a.z, a.w);
    o.z = pack2(b.x, b.y);
    o.w = pack2(b.z, b.w);
    *(uint4*)(Ab + (long)slot * HID + c) = o;
}

// ============ grouped GEMM: 256x128 tile, BK=64, phase-split schedule ========
// A [NSLOT, K] bf16 row-major (compact slots); B [E, N, K] bf16 (B^T layout);
// C [NSLOT, ldc] bf16. Live 256-row m-tiles enumerated by tiles[] table.
//
// R2 theory: R1 showed the stall is the lockstep 2-phase schedule (23% Mfma at
// 3300 cy/K-step vs ~1200 structural), not occupancy/fetch. Port of the
// m201/m248 phase-split schedule (T3+T4+T5):
//   8 waves (2M x 4N), per-wave C = 128x32. 3-slot LDS ring, BK=64.
//   Per K-tile t (slot t%3): one counted vmcnt(6) + barrier at tile top
//   (6 gload_lds/thread/tile; ring depth 3 -> tile t's 6 loads are oldest),
//   then 2 phases, each {issue 3 staging loads for t+2 | 10 ds_read_b128 |
//   setprio(1) 16 MFMA setprio(0)} separated by a barrier. Never vmcnt(0)
//   in steady state; stages for t+2 overwrite slot of t-1, safe because all
//   waves passed tile-t barrier only after consuming t-1.
// LDS swizzle (both-sides, rule #21): 8 chunks (16B) per 64-elem row; chunk c
// of row r stored at pos c ^ (r&7); gload_lds dest stays lane-linear
// (dst elem = tid*8 per 64-row pass), global source pre-swizzled. ds_read_b128
// reads spread 64 lanes over all 8 chunk positions -> minimum 8 dwords/bank,
// conflict-free (SQ_LDS_BANK_CONFLICT = 0 verified R1/R2).
// XCD swizzle (T1): nwg % 8 == 0 (880 / 640).
__device__ __forceinline__ void async16(const u16* g, u16* l) {
    __builtin_amdgcn_global_load_lds(
        (const __attribute__((address_space(1))) void*)g,
        (__attribute__((address_space(3))) void*)l, 16, 0, 0);
}

__global__ __launch_bounds__(512, 2) void gemm_bt(
    const u16* __restrict__ A, const u16* __restrict__ B, u16* __restrict__ C,
    const int* __restrict__ offs, const int* __restrict__ tiles,
    int N, int K, int ldc, int Mtot) {
    // ---- XCD-aware block remap (grid is x-fastest; nwg % 8 == 0) ----
    int gx = gridDim.x;
    int nwg = gx * gridDim.y;
    int flat = blockIdx.y * gx + blockIdx.x;
    int cpx = nwg >> 3;
    int wg = (flat & 7) * cpx + (flat >> 3);
    int bx = wg % gx, by = wg / gx;

    int ent = tiles[bx];
    if (ent < 0) return;
    int e = ent >> 20;
    int m0 = ent & 0xFFFFF;
    int m_base = offs[e];
    int m_cnt = offs[e + 1] - m_base;
    int n0 = by * 128;

    // 3-slot ring: A 3x(256x64) = 96 KB, B 3x(128x64) = 48 KB -> 144 KB
    __shared__ u16 As[3 * 256 * 64];
    __shared__ u16 Bs[3 * 128 * 64];

    int tid = threadIdx.x;
    int lane = tid & 63;
    int wave = tid >> 6;
    const u16* Be = B + (long)e * N * K;

    // ---- staging addresses: thread handles row r0 = tid>>3, chunk d = tid&7
    // (and rows +64/+128/+192 for A, +64 for B). Source chunk pre-swizzled:
    // src = (d ^ (r0&7)); +64 row steps preserve (r&7). Dest = tid*8 per pass.
    int r0 = tid >> 3;
    int srcC = (((tid & 7) ^ (r0 & 7)) * 8);
    int rA0 = m_base + m0 + r0;
    int rA1 = rA0 + 64, rA2 = rA0 + 128, rA3 = rA0 + 192;
    if (rA0 > Mtot - 1) rA0 = Mtot - 1;   // clamp: garbage rows masked at store
    if (rA1 > Mtot - 1) rA1 = Mtot - 1;
    if (rA2 > Mtot - 1) rA2 = Mtot - 1;
    if (rA3 > Mtot - 1) rA3 = Mtot - 1;
    const u16* gA0 = A + (long)rA0 * K + srcC;
    const u16* gA1 = A + (long)rA1 * K + srcC;
    const u16* gA2 = A + (long)rA2 * K + srcC;
    const u16* gA3 = A + (long)rA3 * K + srcC;
    const u16* gB0 = Be + (long)(n0 + r0) * K + srcC;
    const u16* gB1 = Be + (long)(n0 + 64 + r0) * K + srcC;

    auto stage_half = [&](int t, int h) {
        int s = t % 3;
        int ko = t << 6;   // elems
        u16* as = As + s * 16384;
        u16* bs = Bs + s * 8192;
        if (h == 0) {
            async16(gA0 + ko, as + tid * 8);
            async16(gA1 + ko, as + 4096 + tid * 8);
            async16(gB0 + ko, bs + tid * 8);
        } else {
            async16(gA2 + ko, as + 8192 + tid * 8);
            async16(gA3 + ko, as + 12288 + tid * 8);
            async16(gB1 + ko, bs + 4096 + tid * 8);
        }
    };

    // wave -> C sub-tile: 2M x 4N; per-wave 128 x 32
    int wm = (wave >> 2) * 128;
    int wn = (wave & 3) * 32;
    int fr = lane & 15;
    int l47 = lane >> 4, lx = lane & 7;
    // read-side chunk position for k-half ks: ((ks*4 + l47) ^ lx) * 8 elems
    int pA0 = ((l47) ^ lx) * 8;
    int pA1 = ((4 + l47) ^ lx) * 8;

    f32x4_t acc[8][2] = {};

    int NT = K >> 6;
    stage_half(0, 0); stage_half(0, 1);
    stage_half(1, 0); stage_half(1, 1);
    for (int t = 0; t < NT; ++t) {
        // tile t's 6 loads are the oldest outstanding; t+1's 6 may stay in flight
        if (t + 1 < NT) asm volatile("s_waitcnt vmcnt(6)" ::: "memory");
        else            asm volatile("s_waitcnt vmcnt(0)" ::: "memory");
        __builtin_amdgcn_s_barrier();
        asm volatile("" ::: "memory");

        const u16* Ap = As + (t % 3) * 16384 + (wm + fr) * 64;
        const u16* Bp = Bs + (t % 3) * 8192 + (wn + fr) * 64;

        // ---- phase 0 (k 0..31) ----
        if (t + 2 < NT) stage_half(t + 2, 0);
        {
            bf16x8_t av[8], bv[2];
            #pragma unroll
            for (int i = 0; i < 8; ++i) av[i] = *(const bf16x8_t*)(Ap + i * 1024 + pA0);
            #pragma unroll
            for (int j = 0; j < 2; ++j) bv[j] = *(const bf16x8_t*)(Bp + j * 1024 + pA0);
            __builtin_amdgcn_s_setprio(1);
            #pragma unroll
            for (int i = 0; i < 8; ++i)
                #pragma unroll
                for (int j = 0; j < 2; ++j)
                    acc[i][j] = __builtin_amdgcn_mfma_f32_16x16x32_bf16(av[i], bv[j], acc[i][j], 0, 0, 0);
            __builtin_amdgcn_s_setprio(0);
        }
        __builtin_amdgcn_s_barrier();
        asm volatile("" ::: "memory");

        // ---- phase 1 (k 32..63) ----
        if (t + 2 < NT) stage_half(t + 2, 1);
        {
            bf16x8_t av[8], bv[2];
            #pragma unroll
            for (int i = 0; i < 8; ++i) av[i] = *(const bf16x8_t*)(Ap + i * 1024 + pA1);
            #pragma unroll
            for (int j = 0; j < 2; ++j) bv[j] = *(const bf16x8_t*)(Bp + j * 1024 + pA1);
            __builtin_amdgcn_s_setprio(1);
            #pragma unroll
            for (int i = 0; i < 8; ++i)
                #pragma unroll
                for (int j = 0; j < 2; ++j)
                    acc[i][j] = __builtin_amdgcn_mfma_f32_16x16x32_bf16(av[i], bv[j], acc[i][j], 0, 0, 0);
            __builtin_amdgcn_s_setprio(0);
        }
    }

    // epilogue: C/D layout col=lane&15, row=(lane>>4)*4+reg  [m89-verified]
    int cr = (lane >> 4) * 4;
    int cc = lane & 15;
    #pragma unroll
    for (int i = 0; i < 8; ++i) {
        #pragma unroll
        for (int j = 0; j < 2; ++j) {
            int gcol = n0 + wn + j * 16 + cc;
            #pragma unroll
            for (int r = 0; r < 4; ++r) {
                int mr = m0 + wm + i * 16 + cr + r;
                if (mr < m_cnt)
                    C[(long)(m_base + mr) * ldc + gcol] = f2bf(acc[i][j][r]);
            }
        }
    }
}

// ---------------- SiLU gate: act = silu(g) * u ----------------
__global__ __launch_bounds__(256) void act_kernel(const u16* __restrict__ h,
                                                  u16* __restrict__ act) {
    long i = (long)blockIdx.x * 256 + threadIdx.x;   // one per 4 elems
    long s = i / (FFN1 / 4);
    int f = (int)(i % (FFN1 / 4)) * 4;
    const u16* hr = h + s * TWO_FFN;
    uint2 gv = *(const uint2*)(hr + f);
    uint2 uv = *(const uint2*)(hr + FFN1 + f);
    float g0 = bf2f((u16)(gv.x & 0xFFFF)), g1 = bf2f((u16)(gv.x >> 16));
    float g2 = bf2f((u16)(gv.y & 0xFFFF)), g3 = bf2f((u16)(gv.y >> 16));
    float u0 = bf2f((u16)(uv.x & 0xFFFF)), u1 = bf2f((u16)(uv.x >> 16));
    float u2 = bf2f((u16)(uv.y & 0xFFFF)), u3 = bf2f((u16)(uv.y >> 16));
    float a0 = g0 / (1.f + expf(-g0)) * u0;
    float a1 = g1 / (1.f + expf(-g1)) * u1;
    float a2 = g2 / (1.f + expf(-g2)) * u2;
    float a3 = g3 / (1.f + expf(-g3)) * u3;
    uint2 o;
    o.x = pack2(a0, a1);
    o.y = pack2(a2, a3);
    *(uint2*)(act + s * FFN1 + f) = o;
}

// ---------------- combine: out[t] = w0*y[slot0] + w1*y[slot1] ----------------
__global__ __launch_bounds__(256) void combine_kernel(
    const u16* __restrict__ y, const int* __restrict__ inv,
    const float2* __restrict__ wts, float* __restrict__ out) {
    int t = blockIdx.x >> 1;
    int c = ((blockIdx.x & 1) << 10) + threadIdx.x * 4;
    int s0 = inv[2 * t], s1 = inv[2 * t + 1];
    float2 w = wts[t];
    uint2 a = *(const uint2*)(y + (long)s0 * HID + c);
    uint2 b = *(const uint2*)(y + (long)s1 * HID + c);
    float4 o;
    o.x = w.x * bf2f((u16)(a.x & 0xFFFF)) + w.y * bf2f((u16)(b.x & 0xFFFF));
    o.y = w.x * bf2f((u16)(a.x >> 16))   + w.y * bf2f((u16)(b.x >> 16));
    o.z = w.x * bf2f((u16)(a.y & 0xFFFF)) + w.y * bf2f((u16)(b.y & 0xFFFF));
    o.w = w.x * bf2f((u16)(a.y >> 16))   + w.y * bf2f((u16)(b.y >> 16));
    *(float4*)(out + (long)t * HID + c) = o;
}

extern "C" void kernel_launch(void* const* d_in, const int* in_sizes, int n_in,
                              void* d_out, int out_size, void* d_ws, size_t ws_size,
                              hipStream_t stream) {
    const float* hidden = (const float*)d_in[0];   // [4096, 2048]
    const float* gate_w = (const float*)d_in[1];   // [2048, 8]
    const float* w1     = (const float*)d_in[2];   // [8, 2816, 2048]
    const float* w2     = (const float*)d_in[3];   // [8, 2048, 1408]
    float* out_final  = (float*)d_out;                       // [4096, 2048]
    float* out_logits = out_final + (long)T_SEQ * HID;       // [4096, 8]

    const long W1N = (long)NE * TWO_FFN * HID;   // 46,137,344 elems
    const long W2N = (long)NE * HID * FFN1;      // 23,068,672
    const long ABN = (long)NSLOT * HID;          // 16,777,216
    const long HN  = (long)NSLOT * TWO_FFN;      // 23,068,672

    u16* w1b = (u16*)d_ws;
    u16* w2b = w1b + W1N;
    u16* Ab  = w2b + W2N;
    u16* h   = Ab + ABN;
    int* counts = (int*)(h + HN);
    int* cursor = counts + 8;
    int* offs   = counts + 16;    // 9 ints (padded region)
    int* pairs  = counts + 32;
    float2* wts = (float2*)(pairs + T_SEQ);
    int* tok_of = (int*)(wts + T_SEQ);
    int* inv    = tok_of + NSLOT;
    int* tiles  = inv + 2 * T_SEQ;   // MAXT ints
    u16* act = w1b;   // alias: w1b dead after GEMM1
    u16* yb  = Ab;    // alias: Ab dead after GEMM1

    hipMemsetAsync(counts, 0, 64, stream);   // counts[8] + cursor[8]
    router_kernel<<<T_SEQ / 4, 256, 0, stream>>>(hidden, gate_w, out_logits, pairs, wts, counts);
    offsets_kernel<<<1, 64, 0, stream>>>(counts, offs, tiles);
    scatter_kernel<<<T_SEQ / 256, 256, 0, stream>>>(pairs, offs, cursor, tok_of, inv);
    gather_kernel<<<NSLOT, 256, 0, stream>>>(hidden, tok_of, Ab);
    cvt_kernel<<<(int)(W1N / 2048), 256, 0, stream>>>(w1, w1b, W1N);
    cvt_kernel<<<(int)(W2N / 2048), 256, 0, stream>>>(w2, w2b, W2N);
    // GEMM1: 256x128 tiles, grid 40 x 22 = 880 blocks (nwg % 8 == 0)
    gemm_bt<<<dim3(MAXT, TWO_FFN / 128), 512, 0, stream>>>(
        Ab, w1b, h, offs, tiles, TWO_FFN, HID, TWO_FFN, NSLOT);
    act_kernel<<<(int)((long)NSLOT * FFN1 / 4 / 256), 256, 0, stream>>>(h, act);
    // GEMM2: 256x128 tiles, grid 40 x 16 = 640 blocks (nwg % 8 == 0)
    gemm_bt<<<dim3(MAXT, HID / 128), 512, 0, stream>>>(
        act, w2b, yb, offs, tiles, HID, FFN1, HID, NSLOT);
    combine_kernel<<<NSLOT, 256, 0, stream>>>(yb, inv, wts, out_final);
}

// Round 4
// 771.970 us; speedup vs baseline: 1.2018x; 1.2018x over previous
//
#include <hip/hip_runtime.h>
#include <math.h>

#define T_SEQ 4096
#define HID 2048
#define FFN1 1408
#define TWO_FFN 2816
#define NE 8
#define NSLOT 8192   // T_SEQ * TOP_K
#define MAXT 72      // max live m-tiles at 128-granule: 8192/128 + 8
#define W1N_C 46137344L
#define W2N_C 23068672L

typedef unsigned short u16;
typedef __bf16 bf16x8_t __attribute__((ext_vector_type(8)));
typedef float f32x4_t __attribute__((ext_vector_type(4)));

__device__ __forceinline__ u16 f2bf(float f) {
    union { float f; unsigned int u; } v; v.f = f;
    unsigned int u = v.u;
    unsigned int r = u + 0x7FFFu + ((u >> 16) & 1u);
    return (u16)(r >> 16);
}
__device__ __forceinline__ float bf2f(u16 b) {
    union { unsigned int u; float f; } v; v.u = ((unsigned int)b) << 16;
    return v.f;
}
__device__ __forceinline__ unsigned pack2(float a, float b) {
    return (unsigned)f2bf(a) | ((unsigned)f2bf(b) << 16);
}

// ------- fp32 -> bf16 bulk convert, both weight tensors in one launch -------
__global__ __launch_bounds__(256) void cvt_all_kernel(
    const float* __restrict__ w1, const float* __restrict__ w2,
    u16* __restrict__ o1, u16* __restrict__ o2) {
    long i = ((long)blockIdx.x * 256 + threadIdx.x) * 8;
    const float* in; u16* out; long off;
    if (i < W1N_C) { in = w1; out = o1; off = i; }
    else           { in = w2; out = o2; off = i - W1N_C; }
    const float4* p = (const float4*)(in + off);
    float4 a = p[0], b = p[1];
    uint4 o;
    o.x = pack2(a.x, a.y);
    o.y = pack2(a.z, a.w);
    o.z = pack2(b.x, b.y);
    o.w = pack2(b.z, b.w);
    *(uint4*)(out + off) = o;
}

// ---------------- router: logits, top-2, weights, counts ----------------
__global__ __launch_bounds__(256) void router_kernel(
    const float* __restrict__ x, const float* __restrict__ gw,
    float* __restrict__ logits_out, int* __restrict__ pairs,
    float2* __restrict__ wts, int* __restrict__ counts) {
    int wave = threadIdx.x >> 6, lane = threadIdx.x & 63;
    int t = blockIdx.x * 4 + wave;
    float acc[NE] = {0.f,0.f,0.f,0.f,0.f,0.f,0.f,0.f};
    const float* xr = x + (long)t * HID;
    for (int i = 0; i < HID / 64; ++i) {
        int hh = i * 64 + lane;
        float xv = xr[hh];
        const float4* g4 = (const float4*)(gw + (long)hh * NE);
        float4 g0 = g4[0], g1 = g4[1];
        acc[0] += xv * g0.x; acc[1] += xv * g0.y;
        acc[2] += xv * g0.z; acc[3] += xv * g0.w;
        acc[4] += xv * g1.x; acc[5] += xv * g1.y;
        acc[6] += xv * g1.z; acc[7] += xv * g1.w;
    }
    #pragma unroll
    for (int m = 1; m < 64; m <<= 1) {
        #pragma unroll
        for (int e = 0; e < NE; ++e) acc[e] += __shfl_xor(acc[e], m, 64);
    }
    if (lane == 0) {
        float* lo = logits_out + (long)t * NE;
        #pragma unroll
        for (int e = 0; e < NE; ++e) lo[e] = acc[e];
        int a = 0; float va = acc[0];
        #pragma unroll
        for (int e = 1; e < NE; ++e) if (acc[e] > va) { va = acc[e]; a = e; }
        int b = -1; float vb = 0.f;
        #pragma unroll
        for (int e = 0; e < NE; ++e) {
            if (e == a) continue;
            if (b < 0 || acc[e] > vb) { vb = acc[e]; b = e; }
        }
        float w0 = 1.0f / (1.0f + expf(vb - va));
        pairs[t] = a | (b << 8);
        wts[t] = make_float2(w0, 1.0f - w0);
        atomicAdd(counts + a, 1);
        atomicAdd(counts + b, 1);
    }
}

// ------- prefix offsets + live-tile table (one wave, shfl scans) -------
__global__ void offsets_kernel(const int* __restrict__ counts, int* __restrict__ offs,
                               int* __restrict__ tiles) {
    int lane = threadIdx.x;   // 64 threads
    int c = (lane < NE) ? counts[lane] : 0;
    int s = c;
    #pragma unroll
    for (int m = 1; m < NE; m <<= 1) {
        int t = __shfl_up(s, m, 64);
        if (lane >= m) s += t;
    }
    if (lane < NE) offs[lane] = s - c;
    if (lane == NE - 1) offs[NE] = s;
    int nt = (lane < NE) ? ((c + 127) >> 7) : 0;   // 128-row m-tiles
    int ts = nt;
    #pragma unroll
    for (int m = 1; m < NE; m <<= 1) {
        int t = __shfl_up(ts, m, 64);
        if (lane >= m) ts += t;
    }
    int tbase = ts - nt;
    if (lane < NE)
        for (int i = 0; i < nt; ++i) tiles[tbase + i] = (lane << 20) | (i << 7);
    int nt_tot = __shfl(ts, NE - 1, 64);
    for (int j = lane; j < MAXT; j += 64)
        if (j >= nt_tot) tiles[j] = -1;
}

// ---------------- scatter tokens into compact expert segments ----------------
__global__ __launch_bounds__(256) void scatter_kernel(
    const int* __restrict__ pairs, const int* __restrict__ offs,
    int* __restrict__ cursor, int* __restrict__ tok_of, int* __restrict__ inv) {
    int t = blockIdx.x * 256 + threadIdx.x;
    if (t >= T_SEQ) return;
    int pr = pairs[t];
    int a = pr & 0xFF, b = (pr >> 8) & 0xFF;
    int p0 = atomicAdd(cursor + a, 1);
    int s0 = offs[a] + p0;
    tok_of[s0] = t; inv[2 * t] = s0;
    int p1 = atomicAdd(cursor + b, 1);
    int s1 = offs[b] + p1;
    tok_of[s1] = t; inv[2 * t + 1] = s1;
}

// ---------------- gather hidden rows to compact bf16 A ----------------
__global__ __launch_bounds__(256) void gather_kernel(
    const float* __restrict__ x, const int* __restrict__ tok_of, u16* __restrict__ Ab) {
    int slot = blockIdx.x;
    int tok = tok_of[slot];
    int c = threadIdx.x * 8;
    const float4* p = (const float4*)(x + (long)tok * HID + c);
    float4 a = p[0], b = p[1];
    uint4 o;
    o.x = pack2(a.x, a.y);
    o.y = pack2(a.z, a.w);
    o.z = pack2(b.x, b.y);
    o.w = pack2(b.z, b.w);
    *(uint4*)(Ab + (long)slot * HID + c) = o;
}

// ================== grouped GEMM, 128x128 tiles, 3 blocks/CU ==================
// R1-proven K-loop (181 us gemm1, MfmaUtil 23%, bank-conflict 0): 3-slot LDS
// ring, counted vmcnt(4), 4 waves (2Mx2N, 64x64 per wave), XOR chunk swizzle
// (both-sides, rule #21), XCD-aware remap. DO NOT touch the sync structure.
//
// FUSED=true (gemm1): block's B-tile = 64 gate rows [n0,n0+64) + 64 up rows
// [FFN1+n0, FFN1+n0+64) -> each wave holds acc_g (bv[0..1]) and acc_u
// (bv[2..3]) for the SAME (row, f-col) -> epilogue computes silu(g)*u fully
// in-register, writes act bf16 directly. Kills act_kernel + h buffer.
// FUSED=false (gemm2): plain 128-col B panel, plain epilogue.
__device__ __forceinline__ void async16(const u16* g, u16* l) {
    __builtin_amdgcn_global_load_lds(
        (const __attribute__((address_space(1))) void*)g,
        (__attribute__((address_space(3))) void*)l, 16, 0, 0);
}

template<bool FUSED>
__global__ __launch_bounds__(256, 3) void gemm_bt(
    const u16* __restrict__ A, const u16* __restrict__ B, u16* __restrict__ C,
    const int* __restrict__ offs, const int* __restrict__ tiles,
    int N, int K, int ldc, int Mtot) {
    // ---- XCD-aware block remap (grid is x-fastest; nwg % 8 == 0) ----
    int gx = gridDim.x;
    int nwg = gx * gridDim.y;
    int flat = blockIdx.y * gx + blockIdx.x;
    int cpx = nwg >> 3;
    int wg = (flat & 7) * cpx + (flat >> 3);
    int bx = wg % gx, by = wg / gx;

    int ent = tiles[bx];
    if (ent < 0) return;
    int e = ent >> 20;
    int m0 = ent & 0xFFFFF;
    int m_base = offs[e];
    int m_cnt = offs[e + 1] - m_base;
    int n0 = by * (FUSED ? 64 : 128);

    // 3-slot ring: 3 x (128 rows x 32 cols) bf16 = 3 x 8 KB each side = 48 KB
    __shared__ u16 As[3 * 128 * 32];
    __shared__ u16 Bs[3 * 128 * 32];

    int tid = threadIdx.x;
    int lane = tid & 63;
    int wave = tid >> 6;
    const u16* Be = B + (long)e * N * K;

    // staging: thread stages rows (tid>>2) and (tid>>2)+64, dest chunk tid&3;
    // global source chunk XOR-swizzled so the LDS write stays linear.
    // Note: +64 row steps preserve ((row>>1)&3), so the same offset works.
    int r0 = tid >> 2;
    int cA = ((tid & 3) ^ ((r0 >> 1) & 3)) * 8;
    int rA0 = m_base + m0 + r0;
    int rA1 = rA0 + 64;
    if (rA0 > Mtot - 1) rA0 = Mtot - 1;   // clamp: garbage rows masked at store
    if (rA1 > Mtot - 1) rA1 = Mtot - 1;
    const u16* gA0 = A + (long)rA0 * K + cA;
    const u16* gA1 = A + (long)rA1 * K + cA;
    // B rows: FUSED -> gate row n0+r0 (Bs rows 0-63) + up row FFN1+n0+r0
    // (Bs rows 64-127); else contiguous 128-col panel.
    int b0 = n0 + r0;
    int b1 = (FUSED ? FFN1 + n0 : n0 + 64) + r0;
    const u16* gB0 = Be + (long)b0 * K + cA;
    const u16* gB1 = Be + (long)b1 * K + cA;

    auto stage = [&](int t, int s) {
        int ko = t << 5;
        u16* as = As + s * 4096;
        u16* bs = Bs + s * 4096;
        async16(gA0 + ko, as + tid * 8);
        async16(gA1 + ko, as + 2048 + tid * 8);
        async16(gB0 + ko, bs + tid * 8);
        async16(gB1 + ko, bs + 2048 + tid * 8);
    };

    // 4 waves = 2M x 2N; per-wave 64 rows x (FUSED: 32 g-cols + 32 u-cols,
    // else 64 cols) -> 4x4 MFMA fragments either way.
    int wm = (wave >> 1) * 64;
    int wn = (wave & 1) * (FUSED ? 32 : 64);
    int fr = lane & 15;
    int kg = ((lane >> 4) ^ ((lane >> 1) & 3)) * 8;   // read-side XOR swizzle

    // B fragment row bases: FUSED -> {g, g+16, u, u+16}; else {0,16,32,48}+wn
    int br0 = wn;
    int br1 = wn + 16;
    int br2 = FUSED ? (64 + wn) : (wn + 32);
    int br3 = FUSED ? (64 + wn + 16) : (wn + 48);

    f32x4_t acc[4][4] = {};

    int NT = K >> 5;
    stage(0, 0); stage(1, 1);
    int sl = 0;   // slot holding tile t
    for (int t = 0; t < NT; ++t) {
        // own loads for tile t landed: outstanding allowed = tile t+1 only (4)
        if (t + 1 < NT) asm volatile("s_waitcnt vmcnt(4)" ::: "memory");
        else            asm volatile("s_waitcnt vmcnt(0)" ::: "memory");
        __builtin_amdgcn_s_barrier();
        asm volatile("" ::: "memory");
        int s2 = sl + 2; if (s2 >= 3) s2 -= 3;
        if (t + 2 < NT) stage(t + 2, s2);

        const u16* Ap = As + sl * 4096;
        const u16* Bp = Bs + sl * 4096;
        bf16x8_t av[4], bv[4];
        #pragma unroll
        for (int i = 0; i < 4; ++i)
            av[i] = *(const bf16x8_t*)(Ap + (wm + i * 16 + fr) * 32 + kg);
        bv[0] = *(const bf16x8_t*)(Bp + (br0 + fr) * 32 + kg);
        bv[1] = *(const bf16x8_t*)(Bp + (br1 + fr) * 32 + kg);
        bv[2] = *(const bf16x8_t*)(Bp + (br2 + fr) * 32 + kg);
        bv[3] = *(const bf16x8_t*)(Bp + (br3 + fr) * 32 + kg);
        #pragma unroll
        for (int i = 0; i < 4; ++i)
            #pragma unroll
            for (int j = 0; j < 4; ++j)
                acc[i][j] = __builtin_amdgcn_mfma_f32_16x16x32_bf16(av[i], bv[j], acc[i][j], 0, 0, 0);
        sl = (sl == 2) ? 0 : sl + 1;
    }

    // epilogue: C/D layout col=lane&15, row=(lane>>4)*4+reg  [m89-verified]
    int cr = (lane >> 4) * 4;
    int cc = lane & 15;
    if constexpr (FUSED) {
        // acc[i][j] = gate, acc[i][j+2] = up for the same output column.
        #pragma unroll
        for (int i = 0; i < 4; ++i) {
            #pragma unroll
            for (int j = 0; j < 2; ++j) {
                int gcol = n0 + wn + j * 16 + cc;
                #pragma unroll
                for (int r = 0; r < 4; ++r) {
                    int mr = m0 + wm + i * 16 + cr + r;
                    if (mr < m_cnt) {
                        float g = acc[i][j][r];
                        float u = acc[i][j + 2][r];
                        float a = g / (1.f + expf(-g)) * u;
                        C[(long)(m_base + mr) * ldc + gcol] = f2bf(a);
                    }
                }
            }
        }
    } else {
        #pragma unroll
        for (int i = 0; i < 4; ++i) {
            #pragma unroll
            for (int j = 0; j < 4; ++j) {
                int gcol = n0 + wn + j * 16 + cc;
                #pragma unroll
                for (int r = 0; r < 4; ++r) {
                    int mr = m0 + wm + i * 16 + cr + r;
                    if (mr < m_cnt)
                        C[(long)(m_base + mr) * ldc + gcol] = f2bf(acc[i][j][r]);
                }
            }
        }
    }
}

// ---------------- combine: out[t] = w0*y[slot0] + w1*y[slot1] ----------------
__global__ __launch_bounds__(256) void combine_kernel(
    const u16* __restrict__ y, const int* __restrict__ inv,
    const float2* __restrict__ wts, float* __restrict__ out) {
    int t = blockIdx.x >> 1;
    int c = ((blockIdx.x & 1) << 10) + threadIdx.x * 4;
    int s0 = inv[2 * t], s1 = inv[2 * t + 1];
    float2 w = wts[t];
    uint2 a = *(const uint2*)(y + (long)s0 * HID + c);
    uint2 b = *(const uint2*)(y + (long)s1 * HID + c);
    float4 o;
    o.x = w.x * bf2f((u16)(a.x & 0xFFFF)) + w.y * bf2f((u16)(b.x & 0xFFFF));
    o.y = w.x * bf2f((u16)(a.x >> 16))   + w.y * bf2f((u16)(b.x >> 16));
    o.z = w.x * bf2f((u16)(a.y & 0xFFFF)) + w.y * bf2f((u16)(b.y & 0xFFFF));
    o.w = w.x * bf2f((u16)(a.y >> 16))   + w.y * bf2f((u16)(b.y >> 16));
    *(float4*)(out + (long)t * HID + c) = o;
}

extern "C" void kernel_launch(void* const* d_in, const int* in_sizes, int n_in,
                              void* d_out, int out_size, void* d_ws, size_t ws_size,
                              hipStream_t stream) {
    const float* hidden = (const float*)d_in[0];   // [4096, 2048]
    const float* gate_w = (const float*)d_in[1];   // [2048, 8]
    const float* w1     = (const float*)d_in[2];   // [8, 2816, 2048]
    const float* w2     = (const float*)d_in[3];   // [8, 2048, 1408]
    float* out_final  = (float*)d_out;                       // [4096, 2048]
    float* out_logits = out_final + (long)T_SEQ * HID;       // [4096, 8]

    const long W1N = W1N_C;                      // 46,137,344 elems
    const long W2N = W2N_C;                      // 23,068,672
    const long ABN = (long)NSLOT * HID;          // 16,777,216
    const long HN  = (long)NSLOT * TWO_FFN;      // region kept for act (uses half)

    u16* w1b = (u16*)d_ws;
    u16* w2b = w1b + W1N;
    u16* Ab  = w2b + W2N;
    u16* act = Ab + ABN;          // [NSLOT, FFN1] bf16 (in old h region)
    int* counts = (int*)(act + HN);
    int* cursor = counts + 8;
    int* offs   = counts + 16;    // 9 ints (padded region)
    int* pairs  = counts + 32;
    float2* wts = (float2*)(pairs + T_SEQ);
    int* tok_of = (int*)(wts + T_SEQ);
    int* inv    = tok_of + NSLOT;
    int* tiles  = inv + 2 * T_SEQ;   // MAXT ints
    u16* yb  = Ab;    // alias: Ab dead after GEMM1

    hipMemsetAsync(counts, 0, 64, stream);   // counts[8] + cursor[8]
    router_kernel<<<T_SEQ / 4, 256, 0, stream>>>(hidden, gate_w, out_logits, pairs, wts, counts);
    offsets_kernel<<<1, 64, 0, stream>>>(counts, offs, tiles);
    scatter_kernel<<<T_SEQ / 256, 256, 0, stream>>>(pairs, offs, cursor, tok_of, inv);
    gather_kernel<<<NSLOT, 256, 0, stream>>>(hidden, tok_of, Ab);
    cvt_all_kernel<<<(int)((W1N + W2N) / 2048), 256, 0, stream>>>(w1, w2, w1b, w2b);
    // GEMM1 (fused SiLU): 128-row x (64 gate + 64 up) tiles,
    // grid 72 x 22 = 1584 blocks (nwg % 8 == 0); writes act [NSLOT, FFN1]
    gemm_bt<true><<<dim3(MAXT, FFN1 / 64), 256, 0, stream>>>(
        Ab, w1b, act, offs, tiles, TWO_FFN, HID, FFN1, NSLOT);
    // GEMM2: 128x128 tiles, grid 72 x 16 = 1152 blocks (nwg % 8 == 0)
    gemm_bt<false><<<dim3(MAXT, HID / 128), 256, 0, stream>>>(
        act, w2b, yb, offs, tiles, HID, FFN1, HID, NSLOT);
    combine_kernel<<<NSLOT, 256, 0, stream>>>(yb, inv, wts, out_final);
}

// Round 6
// 771.571 us; speedup vs baseline: 1.2024x; 1.0005x over previous
//
#include <hip/hip_runtime.h>
#include <math.h>

#define T_SEQ 4096
#define HID 2048
#define FFN1 1408
#define TWO_FFN 2816
#define NE 8
#define NSLOT 8192   // T_SEQ * TOP_K
#define MAXT 72      // max live m-tiles at 128-granule: 8192/128 + 8
#define W1N_C 46137344L
#define W2N_C 23068672L

typedef unsigned short u16;
typedef __bf16 bf16x8_t __attribute__((ext_vector_type(8)));
typedef float f32x4_t __attribute__((ext_vector_type(4)));

__device__ __forceinline__ u16 f2bf(float f) {
    union { float f; unsigned int u; } v; v.f = f;
    unsigned int u = v.u;
    unsigned int r = u + 0x7FFFu + ((u >> 16) & 1u);
    return (u16)(r >> 16);
}
__device__ __forceinline__ float bf2f(u16 b) {
    union { unsigned int u; float f; } v; v.u = ((unsigned int)b) << 16;
    return v.f;
}
__device__ __forceinline__ unsigned pack2(float a, float b) {
    return (unsigned)f2bf(a) | ((unsigned)f2bf(b) << 16);
}

// ------- fp32 -> bf16 bulk convert, both weight tensors in one launch -------
__global__ __launch_bounds__(256) void cvt_all_kernel(
    const float* __restrict__ w1, const float* __restrict__ w2,
    u16* __restrict__ o1, u16* __restrict__ o2) {
    long i = ((long)blockIdx.x * 256 + threadIdx.x) * 8;
    const float* in; u16* out; long off;
    if (i < W1N_C) { in = w1; out = o1; off = i; }
    else           { in = w2; out = o2; off = i - W1N_C; }
    const float4* p = (const float4*)(in + off);
    float4 a = p[0], b = p[1];
    uint4 o;
    o.x = pack2(a.x, a.y);
    o.y = pack2(a.z, a.w);
    o.z = pack2(b.x, b.y);
    o.w = pack2(b.z, b.w);
    *(uint4*)(out + off) = o;
}

// ---------------- router: logits, top-2, weights, counts ----------------
__global__ __launch_bounds__(256) void router_kernel(
    const float* __restrict__ x, const float* __restrict__ gw,
    float* __restrict__ logits_out, int* __restrict__ pairs,
    float2* __restrict__ wts, int* __restrict__ counts) {
    int wave = threadIdx.x >> 6, lane = threadIdx.x & 63;
    int t = blockIdx.x * 4 + wave;
    float acc[NE] = {0.f,0.f,0.f,0.f,0.f,0.f,0.f,0.f};
    const float* xr = x + (long)t * HID;
    for (int i = 0; i < HID / 64; ++i) {
        int hh = i * 64 + lane;
        float xv = xr[hh];
        const float4* g4 = (const float4*)(gw + (long)hh * NE);
        float4 g0 = g4[0], g1 = g4[1];
        acc[0] += xv * g0.x; acc[1] += xv * g0.y;
        acc[2] += xv * g0.z; acc[3] += xv * g0.w;
        acc[4] += xv * g1.x; acc[5] += xv * g1.y;
        acc[6] += xv * g1.z; acc[7] += xv * g1.w;
    }
    #pragma unroll
    for (int m = 1; m < 64; m <<= 1) {
        #pragma unroll
        for (int e = 0; e < NE; ++e) acc[e] += __shfl_xor(acc[e], m, 64);
    }
    if (lane == 0) {
        float* lo = logits_out + (long)t * NE;
        #pragma unroll
        for (int e = 0; e < NE; ++e) lo[e] = acc[e];
        int a = 0; float va = acc[0];
        #pragma unroll
        for (int e = 1; e < NE; ++e) if (acc[e] > va) { va = acc[e]; a = e; }
        int b = -1; float vb = 0.f;
        #pragma unroll
        for (int e = 0; e < NE; ++e) {
            if (e == a) continue;
            if (b < 0 || acc[e] > vb) { vb = acc[e]; b = e; }
        }
        float w0 = 1.0f / (1.0f + expf(vb - va));
        pairs[t] = a | (b << 8);
        wts[t] = make_float2(w0, 1.0f - w0);
        atomicAdd(counts + a, 1);
        atomicAdd(counts + b, 1);
    }
}

// ------- prefix offsets + live-tile table (one wave, shfl scans) -------
__global__ void offsets_kernel(const int* __restrict__ counts, int* __restrict__ offs,
                               int* __restrict__ tiles) {
    int lane = threadIdx.x;   // 64 threads
    int c = (lane < NE) ? counts[lane] : 0;
    int s = c;
    #pragma unroll
    for (int m = 1; m < NE; m <<= 1) {
        int t = __shfl_up(s, m, 64);
        if (lane >= m) s += t;
    }
    if (lane < NE) offs[lane] = s - c;
    if (lane == NE - 1) offs[NE] = s;
    int nt = (lane < NE) ? ((c + 127) >> 7) : 0;   // 128-row m-tiles
    int ts = nt;
    #pragma unroll
    for (int m = 1; m < NE; m <<= 1) {
        int t = __shfl_up(ts, m, 64);
        if (lane >= m) ts += t;
    }
    int tbase = ts - nt;
    if (lane < NE)
        for (int i = 0; i < nt; ++i) tiles[tbase + i] = (lane << 20) | (i << 7);
    int nt_tot = __shfl(ts, NE - 1, 64);
    for (int j = lane; j < MAXT; j += 64)
        if (j >= nt_tot) tiles[j] = -1;
}

// ---------------- scatter tokens into compact expert segments ----------------
__global__ __launch_bounds__(256) void scatter_kernel(
    const int* __restrict__ pairs, const int* __restrict__ offs,
    int* __restrict__ cursor, int* __restrict__ tok_of, int* __restrict__ inv) {
    int t = blockIdx.x * 256 + threadIdx.x;
    if (t >= T_SEQ) return;
    int pr = pairs[t];
    int a = pr & 0xFF, b = (pr >> 8) & 0xFF;
    int p0 = atomicAdd(cursor + a, 1);
    int s0 = offs[a] + p0;
    tok_of[s0] = t; inv[2 * t] = s0;
    int p1 = atomicAdd(cursor + b, 1);
    int s1 = offs[b] + p1;
    tok_of[s1] = t; inv[2 * t + 1] = s1;
}

// ---------------- gather hidden rows to compact bf16 A ----------------
__global__ __launch_bounds__(256) void gather_kernel(
    const float* __restrict__ x, const int* __restrict__ tok_of, u16* __restrict__ Ab) {
    int slot = blockIdx.x;
    int tok = tok_of[slot];
    int c = threadIdx.x * 8;
    const float4* p = (const float4*)(x + (long)tok * HID + c);
    float4 a = p[0], b = p[1];
    uint4 o;
    o.x = pack2(a.x, a.y);
    o.y = pack2(a.z, a.w);
    o.z = pack2(b.x, b.y);
    o.w = pack2(b.z, b.w);
    *(uint4*)(Ab + (long)slot * HID + c) = o;
}

// ============ grouped GEMM, 128x128 tiles, 4-slot ring (distance 3) ==========
// R4 change vs R3 (single variable): prefetch distance 2 -> 3. Theory: staging
// loads miss L2/L3 (370 MB HBM fetch vs 125 ideal), latency ~900+ cy; the
// 3-slot ring's 2-step slack was marginal, so step time settled at ~latency/2.
// 4-slot ring (64 KB LDS, 2 blk/CU) gives 3 steps of slack.
// Protocol (same inductive shape as R1's proven one):
//   prologue: stage tiles 0,1,2 into slots 0,1,2.
//   iter t (slot t&3): gate vmcnt(8) [tail 4, then 0] -> tile t's 4 loads
//   landed, t+1/t+2's may fly; s_barrier -> all waves' t-loads landed AND all
//   waves consumed tile t-1; ds_read tile t; stage tile t+3 into slot
//   (t+3)&3 == (t-1)&3 (freed by the barrier argument); 16 MFMA.
// LDS swizzle (both-sides, rule #21): linear LDS dest for global_load_lds,
// pre-swizzled global source chunk p ^ ((row>>1)&3); reads apply same XOR.
// SQ_LDS_BANK_CONFLICT = 0 verified three rounds.
// FUSED=true (gemm1): B-tile = 64 gate rows + 64 matching up rows; epilogue
// computes silu(g)*u in-register, writes act bf16. FUSED=false (gemm2): plain.
__device__ __forceinline__ void async16(const u16* g, u16* l) {
    __builtin_amdgcn_global_load_lds(
        (const __attribute__((address_space(1))) void*)g,
        (__attribute__((address_space(3))) void*)l, 16, 0, 0);
}

template<bool FUSED>
__global__ __launch_bounds__(256, 2) void gemm_bt(
    const u16* __restrict__ A, const u16* __restrict__ B, u16* __restrict__ C,
    const int* __restrict__ offs, const int* __restrict__ tiles,
    int N, int K, int ldc, int Mtot) {
    // ---- XCD-aware block remap (grid is x-fastest; nwg % 8 == 0) ----
    int gx = gridDim.x;
    int nwg = gx * gridDim.y;
    int flat = blockIdx.y * gx + blockIdx.x;
    int cpx = nwg >> 3;
    int wg = (flat & 7) * cpx + (flat >> 3);
    int bx = wg % gx, by = wg / gx;

    int ent = tiles[bx];
    if (ent < 0) return;
    int e = ent >> 20;
    int m0 = ent & 0xFFFFF;
    int m_base = offs[e];
    int m_cnt = offs[e + 1] - m_base;
    int n0 = by * (FUSED ? 64 : 128);

    // 4-slot ring: 4 x (128 rows x 32 cols) bf16 = 4 x 8 KB each side = 64 KB
    __shared__ u16 As[4 * 128 * 32];
    __shared__ u16 Bs[4 * 128 * 32];

    int tid = threadIdx.x;
    int lane = tid & 63;
    int wave = tid >> 6;
    const u16* Be = B + (long)e * N * K;

    // staging: thread stages rows (tid>>2) and (tid>>2)+64, dest chunk tid&3;
    // global source chunk XOR-swizzled so the LDS write stays linear.
    // Note: +64 row steps preserve ((row>>1)&3), so the same offset works.
    int r0 = tid >> 2;
    int cA = ((tid & 3) ^ ((r0 >> 1) & 3)) * 8;
    int rA0 = m_base + m0 + r0;
    int rA1 = rA0 + 64;
    if (rA0 > Mtot - 1) rA0 = Mtot - 1;   // clamp: garbage rows masked at store
    if (rA1 > Mtot - 1) rA1 = Mtot - 1;
    const u16* gA0 = A + (long)rA0 * K + cA;
    const u16* gA1 = A + (long)rA1 * K + cA;
    // B rows: FUSED -> gate row n0+r0 (Bs rows 0-63) + up row FFN1+n0+r0
    // (Bs rows 64-127); else contiguous 128-col panel.
    int b0 = n0 + r0;
    int b1 = (FUSED ? FFN1 + n0 : n0 + 64) + r0;
    const u16* gB0 = Be + (long)b0 * K + cA;
    const u16* gB1 = Be + (long)b1 * K + cA;

    auto stage = [&](int t, int s) {
        int ko = t << 5;
        u16* as = As + s * 4096;
        u16* bs = Bs + s * 4096;
        async16(gA0 + ko, as + tid * 8);
        async16(gA1 + ko, as + 2048 + tid * 8);
        async16(gB0 + ko, bs + tid * 8);
        async16(gB1 + ko, bs + 2048 + tid * 8);
    };

    // 4 waves = 2M x 2N; per-wave 64 rows x (FUSED: 32 g-cols + 32 u-cols,
    // else 64 cols) -> 4x4 MFMA fragments either way.
    int wm = (wave >> 1) * 64;
    int wn = (wave & 1) * (FUSED ? 32 : 64);
    int fr = lane & 15;
    int kg = ((lane >> 4) ^ ((lane >> 1) & 3)) * 8;   // read-side XOR swizzle

    // B fragment row bases: FUSED -> {g, g+16, u, u+16}; else {0,16,32,48}+wn
    int br0 = wn;
    int br1 = wn + 16;
    int br2 = FUSED ? (64 + wn) : (wn + 32);
    int br3 = FUSED ? (64 + wn + 16) : (wn + 48);

    f32x4_t acc[4][4] = {};

    int NT = K >> 5;
    stage(0, 0); stage(1, 1); stage(2, 2);
    for (int t = 0; t < NT; ++t) {
        // gate: tile t's 4 loads landed; tiles t+1,t+2 (8 loads) may stay out
        if (t + 2 < NT)      asm volatile("s_waitcnt vmcnt(8)" ::: "memory");
        else if (t + 1 < NT) asm volatile("s_waitcnt vmcnt(4)" ::: "memory");
        else                 asm volatile("s_waitcnt vmcnt(0)" ::: "memory");
        __builtin_amdgcn_s_barrier();
        asm volatile("" ::: "memory");

        int sl = t & 3;
        const u16* Ap = As + sl * 4096;
        const u16* Bp = Bs + sl * 4096;
        bf16x8_t av[4], bv[4];
        #pragma unroll
        for (int i = 0; i < 4; ++i)
            av[i] = *(const bf16x8_t*)(Ap + (wm + i * 16 + fr) * 32 + kg);
        bv[0] = *(const bf16x8_t*)(Bp + (br0 + fr) * 32 + kg);
        bv[1] = *(const bf16x8_t*)(Bp + (br1 + fr) * 32 + kg);
        bv[2] = *(const bf16x8_t*)(Bp + (br2 + fr) * 32 + kg);
        bv[3] = *(const bf16x8_t*)(Bp + (br3 + fr) * 32 + kg);

        if (t + 3 < NT) stage(t + 3, (t + 3) & 3);

        #pragma unroll
        for (int i = 0; i < 4; ++i)
            #pragma unroll
            for (int j = 0; j < 4; ++j)
                acc[i][j] = __builtin_amdgcn_mfma_f32_16x16x32_bf16(av[i], bv[j], acc[i][j], 0, 0, 0);
    }

    // epilogue: C/D layout col=lane&15, row=(lane>>4)*4+reg  [m89-verified]
    int cr = (lane >> 4) * 4;
    int cc = lane & 15;
    if constexpr (FUSED) {
        // acc[i][j] = gate, acc[i][j+2] = up for the same output column.
        #pragma unroll
        for (int i = 0; i < 4; ++i) {
            #pragma unroll
            for (int j = 0; j < 2; ++j) {
                int gcol = n0 + wn + j * 16 + cc;
                #pragma unroll
                for (int r = 0; r < 4; ++r) {
                    int mr = m0 + wm + i * 16 + cr + r;
                    if (mr < m_cnt) {
                        float g = acc[i][j][r];
                        float u = acc[i][j + 2][r];
                        float a = g / (1.f + expf(-g)) * u;
                        C[(long)(m_base + mr) * ldc + gcol] = f2bf(a);
                    }
                }
            }
        }
    } else {
        #pragma unroll
        for (int i = 0; i < 4; ++i) {
            #pragma unroll
            for (int j = 0; j < 4; ++j) {
                int gcol = n0 + wn + j * 16 + cc;
                #pragma unroll
                for (int r = 0; r < 4; ++r) {
                    int mr = m0 + wm + i * 16 + cr + r;
                    if (mr < m_cnt)
                        C[(long)(m_base + mr) * ldc + gcol] = f2bf(acc[i][j][r]);
                }
            }
        }
    }
}

// ---------------- combine: out[t] = w0*y[slot0] + w1*y[slot1] ----------------
__global__ __launch_bounds__(256) void combine_kernel(
    const u16* __restrict__ y, const int* __restrict__ inv,
    const float2* __restrict__ wts, float* __restrict__ out) {
    int t = blockIdx.x >> 1;
    int c = ((blockIdx.x & 1) << 10) + threadIdx.x * 4;
    int s0 = inv[2 * t], s1 = inv[2 * t + 1];
    float2 w = wts[t];
    uint2 a = *(const uint2*)(y + (long)s0 * HID + c);
    uint2 b = *(const uint2*)(y + (long)s1 * HID + c);
    float4 o;
    o.x = w.x * bf2f((u16)(a.x & 0xFFFF)) + w.y * bf2f((u16)(b.x & 0xFFFF));
    o.y = w.x * bf2f((u16)(a.x >> 16))   + w.y * bf2f((u16)(b.x >> 16));
    o.z = w.x * bf2f((u16)(a.y & 0xFFFF)) + w.y * bf2f((u16)(b.y & 0xFFFF));
    o.w = w.x * bf2f((u16)(a.y >> 16))   + w.y * bf2f((u16)(b.y >> 16));
    *(float4*)(out + (long)t * HID + c) = o;
}

extern "C" void kernel_launch(void* const* d_in, const int* in_sizes, int n_in,
                              void* d_out, int out_size, void* d_ws, size_t ws_size,
                              hipStream_t stream) {
    const float* hidden = (const float*)d_in[0];   // [4096, 2048]
    const float* gate_w = (const float*)d_in[1];   // [2048, 8]
    const float* w1     = (const float*)d_in[2];   // [8, 2816, 2048]
    const float* w2     = (const float*)d_in[3];   // [8, 2048, 1408]
    float* out_final  = (float*)d_out;                       // [4096, 2048]
    float* out_logits = out_final + (long)T_SEQ * HID;       // [4096, 8]

    const long W1N = W1N_C;                      // 46,137,344 elems
    const long W2N = W2N_C;                      // 23,068,672
    const long ABN = (long)NSLOT * HID;          // 16,777,216
    const long HN  = (long)NSLOT * TWO_FFN;      // region kept for act (uses half)

    u16* w1b = (u16*)d_ws;
    u16* w2b = w1b + W1N;
    u16* Ab  = w2b + W2N;
    u16* act = Ab + ABN;          // [NSLOT, FFN1] bf16 (in old h region)
    int* counts = (int*)(act + HN);
    int* cursor = counts + 8;
    int* offs   = counts + 16;    // 9 ints (padded region)
    int* pairs  = counts + 32;
    float2* wts = (float2*)(pairs + T_SEQ);
    int* tok_of = (int*)(wts + T_SEQ);
    int* inv    = tok_of + NSLOT;
    int* tiles  = inv + 2 * T_SEQ;   // MAXT ints
    u16* yb  = Ab;    // alias: Ab dead after GEMM1

    hipMemsetAsync(counts, 0, 64, stream);   // counts[8] + cursor[8]
    router_kernel<<<T_SEQ / 4, 256, 0, stream>>>(hidden, gate_w, out_logits, pairs, wts, counts);
    offsets_kernel<<<1, 64, 0, stream>>>(counts, offs, tiles);
    scatter_kernel<<<T_SEQ / 256, 256, 0, stream>>>(pairs, offs, cursor, tok_of, inv);
    gather_kernel<<<NSLOT, 256, 0, stream>>>(hidden, tok_of, Ab);
    cvt_all_kernel<<<(int)((W1N + W2N) / 2048), 256, 0, stream>>>(w1, w2, w1b, w2b);
    // GEMM1 (fused SiLU): 128-row x (64 gate + 64 up) tiles,
    // grid 72 x 22 = 1584 blocks (nwg % 8 == 0); writes act [NSLOT, FFN1]
    gemm_bt<true><<<dim3(MAXT, FFN1 / 64), 256, 0, stream>>>(
        Ab, w1b, act, offs, tiles, TWO_FFN, HID, FFN1, NSLOT);
    // GEMM2: 128x128 tiles, grid 72 x 16 = 1152 blocks (nwg % 8 == 0)
    gemm_bt<false><<<dim3(MAXT, HID / 128), 256, 0, stream>>>(
        act, w2b, yb, offs, tiles, HID, FFN1, HID, NSLOT);
    combine_kernel<<<NSLOT, 256, 0, stream>>>(yb, inv, wts, out_final);
}